// Round 4
// baseline (287.672 us; speedup 1.0000x reference)
//
#include <hip/hip_runtime.h>
#include <hip/hip_bf16.h>

// Problem constants (fixed by the reference)
#define N_ROWS 262144
#define IN_DIM 128
#define OUT_DIM 128
#define NTYPES 8
#define ROWS_PER_BLOCK 256
#define GROUP_M 32          // rows per group: two 16-row MFMA tiles sharing B
#define MAX_GROUPS 16       // sum ceil(c_t/32) <= 15 for 256 rows / 8 types

typedef short bf16x8 __attribute__((ext_vector_type(8)));   // 8 bf16 in 4 VGPRs
typedef float f32x4 __attribute__((ext_vector_type(4)));    // plain vector: ok for nontemporal builtins

__device__ __forceinline__ unsigned short f2bf_rne(float f) {
    unsigned int u = __float_as_uint(f);
    u += 0x7fff + ((u >> 16) & 1);   // round-nearest-even; inputs finite/normal
    return (unsigned short)(u >> 16);
}

// W [T][IN][OUT] fp32 -> Wb [T][OUT][IN] bf16. 1024 blocks x 128 threads:
// block (t,o), lane i: strided 4B reads (W is 512KB, L2/L3-resident), 2B
// contiguous writes. Wide grid so this kernel is ~2us.
__global__ void __launch_bounds__(128) prep_w_kernel(const float* __restrict__ W,
                                                     unsigned short* __restrict__ Wb) {
    const int t = blockIdx.x >> 7;
    const int o = blockIdx.x & 127;
    const int i = threadIdx.x;
    Wb[(t * OUT_DIM + o) * IN_DIM + i] = f2bf_rne(W[(t * IN_DIM + i) * OUT_DIM + o]);
}

__device__ __forceinline__ bf16x8 cvt_8f32_to_bf16(f32x4 f0, f32x4 f1) {
    union { bf16x8 v; __hip_bfloat162 h[4]; } u;
    u.h[0] = __float22bfloat162_rn(make_float2(f0[0], f0[1]));
    u.h[1] = __float22bfloat162_rn(make_float2(f0[2], f0[3]));
    u.h[2] = __float22bfloat162_rn(make_float2(f1[0], f1[1]));
    u.h[3] = __float22bfloat162_rn(make_float2(f1[2], f1[3]));
    return u.v;
}

__global__ void __launch_bounds__(256, 4) typed_linear_kernel(
        const float* __restrict__ x, const int* __restrict__ xt,
        const unsigned short* __restrict__ Wb, const float* __restrict__ bias,
        float* __restrict__ out) {
    // A-tiles have zero reuse -> load global->VGPR directly (per instruction
    // the wave covers 16 rows x 128B contiguous segments, fully coalesced).
    // 32-row groups: two 16x16x32 C-tiles share each B-fragment set, halving
    // B (L2) traffic and B load instructions per row. No LDS staging, no
    // vmcnt(0) drains -> loads pipeline freely; 16 waves/CU hide HBM latency.
    __shared__ int s_cnt[NTYPES];
    __shared__ int s_cursor[NTYPES];
    __shared__ unsigned short s_list[ROWS_PER_BLOCK];
    __shared__ unsigned char s_gtype[MAX_GROUPS];
    __shared__ short s_gstart[MAX_GROUPS];
    __shared__ unsigned char s_gcnt[MAX_GROUPS];
    __shared__ int s_ngroups;
    __shared__ float s_bias[NTYPES * OUT_DIM];   // 4 KB

    const int tid = threadIdx.x;
    const int row0 = blockIdx.x * ROWS_PER_BLOCK;

    // ---- Phase 1: bucket this block's 256 rows by type ----
    if (tid < NTYPES) s_cnt[tid] = 0;
    __syncthreads();
    const int my_t = xt[row0 + tid];
    atomicAdd(&s_cnt[my_t], 1);
    // Stage all biases to LDS (8*128 floats, 256 threads x float4, coalesced).
    reinterpret_cast<float4*>(s_bias)[tid] = reinterpret_cast<const float4*>(bias)[tid];
    __syncthreads();
    if (tid == 0) {
        int acc = 0, g = 0;
        for (int i = 0; i < NTYPES; ++i) {
            int c = s_cnt[i];
            s_cursor[i] = acc;
            for (int s = 0; s < c; s += GROUP_M) {
                s_gtype[g] = (unsigned char)i;
                s_gstart[g] = (short)(acc + s);
                s_gcnt[g] = (unsigned char)((c - s) < GROUP_M ? (c - s) : GROUP_M);
                ++g;
            }
            acc += c;
        }
        s_ngroups = g;
    }
    __syncthreads();
    {
        int pos = atomicAdd(&s_cursor[my_t], 1);
        s_list[pos] = (unsigned short)tid;
    }
    __syncthreads();

    // ---- Phase 2: per-wave direct-to-register MFMA over 32-row groups ----
    const int wave = tid >> 6;
    const int lane = tid & 63;
    const int m = lane & 15;     // A row / B col / C col within 16-tile
    const int q = lane >> 4;     // quad: A k-chunk = q*8.., C rows = q*4..q*4+3
    const int ngroups = s_ngroups;

    for (int g = wave; g < ngroups; g += 4) {
        const int t  = s_gtype[g];
        const int gs = s_gstart[g];
        const int gc = s_gcnt[g];
        const bool two = (gc > 16);   // wave-uniform: second 16-row tile live?

        // A source rows (clamp padded rows; duplicate reads hit L1).
        const int mm0 = (m < gc) ? m : (gc - 1);
        const float* ap0 = x + (size_t)(row0 + s_list[gs + mm0]) * IN_DIM + q * 8;

        bf16x8 afrag[2][4];
        #pragma unroll
        for (int kc = 0; kc < 4; ++kc) {
            const f32x4 f0 = __builtin_nontemporal_load(
                reinterpret_cast<const f32x4*>(ap0 + kc * 32));
            const f32x4 f1 = __builtin_nontemporal_load(
                reinterpret_cast<const f32x4*>(ap0 + kc * 32 + 4));
            afrag[0][kc] = cvt_8f32_to_bf16(f0, f1);
        }
        if (two) {
            const int r1 = 16 + m;
            const int mm1 = (r1 < gc) ? r1 : (gc - 1);
            const float* ap1 = x + (size_t)(row0 + s_list[gs + mm1]) * IN_DIM + q * 8;
            #pragma unroll
            for (int kc = 0; kc < 4; ++kc) {
                const f32x4 f0 = __builtin_nontemporal_load(
                    reinterpret_cast<const f32x4*>(ap1 + kc * 32));
                const f32x4 f1 = __builtin_nontemporal_load(
                    reinterpret_cast<const f32x4*>(ap1 + kc * 32 + 4));
                afrag[1][kc] = cvt_8f32_to_bf16(f0, f1);
            }
        }

        // Output rows this lane stores (C layout: row = q*4+r, col = m)
        int orow0[4], orow1[4];
        #pragma unroll
        for (int r = 0; r < 4; ++r) {
            const int mr0 = q * 4 + r;
            orow0[r] = (mr0 < gc) ? (row0 + s_list[gs + mr0]) : -1;
            const int mr1 = 16 + q * 4 + r;
            orow1[r] = (mr1 < gc) ? (row0 + s_list[gs + mr1]) : -1;
        }

        const unsigned short* wt = Wb + t * (IN_DIM * OUT_DIM);
        const float* sb = s_bias + t * OUT_DIM;

        // 8 output-col tiles; each B-fragment set feeds both row-tiles.
        if (two) {
            #pragma unroll
            for (int nt = 0; nt < 8; ++nt) {
                const unsigned short* wcol = wt + (nt * 16 + m) * IN_DIM + q * 8;
                bf16x8 bfr[4];
                #pragma unroll
                for (int kc = 0; kc < 4; ++kc)
                    bfr[kc] = *reinterpret_cast<const bf16x8*>(wcol + kc * 32);
                f32x4 acc0 = {0.f, 0.f, 0.f, 0.f};
                f32x4 acc1 = {0.f, 0.f, 0.f, 0.f};
                #pragma unroll
                for (int kc = 0; kc < 4; ++kc) {
                    acc0 = __builtin_amdgcn_mfma_f32_16x16x32_bf16(afrag[0][kc], bfr[kc], acc0, 0, 0, 0);
                    acc1 = __builtin_amdgcn_mfma_f32_16x16x32_bf16(afrag[1][kc], bfr[kc], acc1, 0, 0, 0);
                }
                const float bv = sb[nt * 16 + m];
                #pragma unroll
                for (int r = 0; r < 4; ++r) {
                    if (orow0[r] >= 0)
                        __builtin_nontemporal_store(acc0[r] + bv,
                            &out[(size_t)orow0[r] * OUT_DIM + nt * 16 + m]);
                    if (orow1[r] >= 0)
                        __builtin_nontemporal_store(acc1[r] + bv,
                            &out[(size_t)orow1[r] * OUT_DIM + nt * 16 + m]);
                }
            }
        } else {
            #pragma unroll
            for (int nt = 0; nt < 8; ++nt) {
                const unsigned short* wcol = wt + (nt * 16 + m) * IN_DIM + q * 8;
                bf16x8 bfr[4];
                #pragma unroll
                for (int kc = 0; kc < 4; ++kc)
                    bfr[kc] = *reinterpret_cast<const bf16x8*>(wcol + kc * 32);
                f32x4 acc0 = {0.f, 0.f, 0.f, 0.f};
                #pragma unroll
                for (int kc = 0; kc < 4; ++kc)
                    acc0 = __builtin_amdgcn_mfma_f32_16x16x32_bf16(afrag[0][kc], bfr[kc], acc0, 0, 0, 0);
                const float bv = sb[nt * 16 + m];
                #pragma unroll
                for (int r = 0; r < 4; ++r) {
                    if (orow0[r] >= 0)
                        __builtin_nontemporal_store(acc0[r] + bv,
                            &out[(size_t)orow0[r] * OUT_DIM + nt * 16 + m]);
                }
            }
        }
    }
}

extern "C" void kernel_launch(void* const* d_in, const int* in_sizes, int n_in,
                              void* d_out, int out_size, void* d_ws, size_t ws_size,
                              hipStream_t stream) {
    const float* x  = (const float*)d_in[0];
    const int* xt   = (const int*)d_in[1];
    const float* W  = (const float*)d_in[2];
    const float* b  = (const float*)d_in[3];
    float* out      = (float*)d_out;
    unsigned short* Wb = (unsigned short*)d_ws;   // 8*128*128*2 = 256 KiB scratch

    prep_w_kernel<<<NTYPES * OUT_DIM, 128, 0, stream>>>(W, Wb);
    typed_linear_kernel<<<N_ROWS / ROWS_PER_BLOCK, 256, 0, stream>>>(x, xt, Wb, b, out);
}